// Round 6
// baseline (676.756 us; speedup 1.0000x reference)
//
#include <hip/hip_runtime.h>
#include <hip/hip_bf16.h>

#define N_NODES 100000
#define N_EDGES 800000
#define BGRAPH  4000
#define GNN_IN  428
#define HDIM    64
#define HID     512
#define EMBD    300
#define AIN     1112   // 512 + 600
#define ASTR    1120   // padded A row stride (bf16)
#define CAP     48     // max in-degree capacity (Poisson(8); actual max ~30)
#define LSTR    72     // LDS row stride (ushorts): 2-way bank alias only (free, m136)

typedef unsigned short u16;
typedef short bf16x8 __attribute__((ext_vector_type(8)));   // MFMA A/B frag (8 bf16, 4 VGPRs)
typedef float f32x4  __attribute__((ext_vector_type(4)));   // MFMA C/D frag

__device__ __forceinline__ u16 f2bf(float f) {
    union { float f; unsigned int u; } v; v.f = f;
    unsigned int r = v.u + 0x7FFFu + ((v.u >> 16) & 1u);    // RNE
    return (u16)(r >> 16);
}
__device__ __forceinline__ float bf2f(u16 u) {
    union { unsigned int u; float f; } v; v.u = ((unsigned int)u) << 16;
    return v.f;
}

// ---------------- prep: w0T[n][k] = bf16(w1_0[k][n]), zero-pad k to 448 ----------------
__global__ void k_prep_w0(const float* __restrict__ w, u16* __restrict__ w0T) {
    const int idx = blockIdx.x * 256 + threadIdx.x;
    if (idx >= 64 * 448) return;
    const int n = idx / 448, k = idx - n * 448;
    w0T[idx] = (k < GNN_IN) ? f2bf(w[k * 64 + n]) : (u16)0;
}
// ---------------- prep: fwT[n][k] = bf16(final_w[k][n]), zero-pad k to 1120 ----------------
__global__ void k_prep_fw(const float* __restrict__ fw, u16* __restrict__ fwT) {
    const int idx = blockIdx.x * 256 + threadIdx.x;
    if (idx >= 512 * 1120) return;
    const int n = idx / 1120, k = idx - n * 1120;
    fwT[idx] = (k < AIN) ? f2bf(fw[(size_t)k * 512 + n]) : (u16)0;
}
// ---------------- prep: 5x 64x64 weight transposes in one dispatch ----------------
__global__ void k_prep_w5(const float* __restrict__ wa, const float* __restrict__ wb,
                          const float* __restrict__ wc, const float* __restrict__ wd,
                          const float* __restrict__ we, u16* __restrict__ wT5) {
    const int idx = blockIdx.x * 256 + threadIdx.x;   // 5*4096
    const int seg = idx >> 12, within = idx & 4095;
    const int k = within >> 6, o = within & 63;
    const float* src = (seg == 0) ? wa : (seg == 1) ? wb : (seg == 2) ? wc
                     : (seg == 3) ? wd : we;
    wT5[seg * 4096 + o * 64 + k] = f2bf(src[within]);
}

// ---------------- y = bf16(x @ w1_0) — MFMA, barrier-free, no LDS ----------------
__global__ __launch_bounds__(256) void k_gemm_xw(const float* __restrict__ x,
                                                 const u16* __restrict__ w0T,
                                                 u16* __restrict__ y) {
    const int t = threadIdx.x;
    const int lane = t & 63, wave = t >> 6;
    const int q = lane >> 4, m = lane & 15;
    const int n0 = blockIdx.x * 64;
    const int row = min(n0 + wave * 16 + m, N_NODES - 1);
    const float* __restrict__ xr = &x[(size_t)row * GNN_IN];

    f32x4 acc[4];
#pragma unroll
    for (int c = 0; c < 4; ++c) acc[c] = (f32x4){0.f, 0.f, 0.f, 0.f};

    for (int k0 = 0; k0 < 448; k0 += 32) {
        const int ka = k0 + q * 8;
        float4 va = {0.f, 0.f, 0.f, 0.f}, vb = {0.f, 0.f, 0.f, 0.f};
        if (ka + 4 <= GNN_IN) va = *reinterpret_cast<const float4*>(xr + ka);
        if (ka + 8 <= GNN_IN) vb = *reinterpret_cast<const float4*>(xr + ka + 4);
        bf16x8 a;
        a[0] = (short)f2bf(va.x); a[1] = (short)f2bf(va.y);
        a[2] = (short)f2bf(va.z); a[3] = (short)f2bf(va.w);
        a[4] = (short)f2bf(vb.x); a[5] = (short)f2bf(vb.y);
        a[6] = (short)f2bf(vb.z); a[7] = (short)f2bf(vb.w);
#pragma unroll
        for (int c = 0; c < 4; ++c) {
            const bf16x8 b = *reinterpret_cast<const bf16x8*>(&w0T[(c * 16 + m) * 448 + ka]);
            acc[c] = __builtin_amdgcn_mfma_f32_16x16x32_bf16(a, b, acc[c], 0, 0, 0);
        }
    }
#pragma unroll
    for (int c = 0; c < 4; ++c)
#pragma unroll
        for (int r = 0; r < 4; ++r) {
            const int rr = n0 + wave * 16 + q * 4 + r;
            if (rr < N_NODES) y[(size_t)rr * 64 + c * 16 + m] = f2bf(acc[c][r]);
        }
}

// ---------------- CSR (bucketed) fill ----------------
__global__ void k_fill(const int* __restrict__ ei, int* __restrict__ deg,
                       int* __restrict__ csr2) {
    const int e = blockIdx.x * blockDim.x + threadIdx.x;
    if (e >= N_EDGES) return;
    const int s = ei[e];
    const int d = ei[N_EDGES + e];
    const int slot = atomicAdd(&deg[d], 1);
    if (slot < CAP) csr2[d * CAP + slot] = s;
}

// ---------------- counts[b] = #nodes in segment b ----------------
__global__ void k_counts(const int* __restrict__ bids, float* __restrict__ counts) {
    const int n = blockIdx.x * blockDim.x + threadIdx.x;
    if (n >= N_NODES) return;
    atomicAdd(&counts[bids[n]], 1.0f);
}

// ---------------- aggregation: one node per wave, lane = feature ----------------
// u[n] = h[n] + sum_{j in csr[n]} h[j]; optional fused bias+relu (layer 0).
template <int BIASRELU>
__global__ __launch_bounds__(256, 8) void k_agg(const u16* __restrict__ hin,
                                                const int* __restrict__ deg,
                                                const int* __restrict__ csr2,
                                                const float* __restrict__ b1,
                                                u16* __restrict__ uout) {
    const int wave = threadIdx.x >> 6, lane = threadIdx.x & 63;
    const int n = blockIdx.x * 4 + wave;
    if (n >= N_NODES) return;
    const int dg = min(deg[n], CAP);
    const int4* l4 = reinterpret_cast<const int4*>(&csr2[(size_t)n * CAP]);
    const int4 i0 = l4[0], i1 = l4[1];
    const int id[8] = {i0.x, i0.y, i0.z, i0.w, i1.x, i1.y, i1.z, i1.w};
    float u = bf2f(hin[(size_t)n * 64 + lane]);
    float v[8];
#pragma unroll
    for (int i = 0; i < 8; ++i) {
        const bool ok = (i < dg);
        const int ix = ok ? id[i] : 0;
        v[i] = ok ? bf2f(hin[(size_t)ix * 64 + lane]) : 0.f;
    }
#pragma unroll
    for (int i = 0; i < 8; ++i) u += v[i];
    if (__builtin_expect(dg > 8, 0)) {
        for (int e = 8; e < dg; e += 8) {
            const int4 a4 = l4[e >> 2];
            const int4 b4 = l4[(e >> 2) + 1];
            const int jd[8] = {a4.x, a4.y, a4.z, a4.w, b4.x, b4.y, b4.z, b4.w};
#pragma unroll
            for (int i = 0; i < 8; ++i) {
                const bool ok = (e + i < dg);
                const int ix = ok ? jd[i] : 0;
                u += ok ? bf2f(hin[(size_t)ix * 64 + lane]) : 0.f;
            }
        }
    }
    if (BIASRELU) u = fmaxf(u + b1[lane], 0.f);
    uout[(size_t)n * 64 + lane] = f2bf(u);
}

// ---------------- single-stage MLP: h = relu(z @ w2 + b2) — barrier-free MFMA ----------
__global__ __launch_bounds__(256, 4) void k_mlp1(const u16* __restrict__ z,
                                                 const u16* __restrict__ w2T,
                                                 const float* __restrict__ b2,
                                                 u16* __restrict__ hout) {
    const int t = threadIdx.x;
    const int lane = t & 63, wave = t >> 6;
    const int q = lane >> 4, m = lane & 15;
    const int base = blockIdx.x * 64 + wave * 16;
    const int rowm = min(base + m, N_NODES - 1);
    const bf16x8 a0 = *reinterpret_cast<const bf16x8*>(&z[(size_t)rowm * 64 + q * 8]);
    const bf16x8 a1 = *reinterpret_cast<const bf16x8*>(&z[(size_t)rowm * 64 + 32 + q * 8]);
    f32x4 acc[4];
#pragma unroll
    for (int c = 0; c < 4; ++c) acc[c] = (f32x4){0.f, 0.f, 0.f, 0.f};
#pragma unroll
    for (int c = 0; c < 4; ++c) {
        const bf16x8 bb0 = *reinterpret_cast<const bf16x8*>(&w2T[(c * 16 + m) * 64 + q * 8]);
        const bf16x8 bb1 = *reinterpret_cast<const bf16x8*>(&w2T[(c * 16 + m) * 64 + 32 + q * 8]);
        acc[c] = __builtin_amdgcn_mfma_f32_16x16x32_bf16(a0, bb0, acc[c], 0, 0, 0);
        acc[c] = __builtin_amdgcn_mfma_f32_16x16x32_bf16(a1, bb1, acc[c], 0, 0, 0);
    }
#pragma unroll
    for (int c = 0; c < 4; ++c) {
        const float bb = b2[c * 16 + m];
#pragma unroll
        for (int r = 0; r < 4; ++r) {
            const int n = base + q * 4 + r;
            if (n < N_NODES) hout[(size_t)n * 64 + c * 16 + m] = f2bf(fmaxf(acc[c][r] + bb, 0.f));
        }
    }
}

// two-stage MLP core (barrier-free; zs rows are wave-private)
__device__ __forceinline__ void mlp2_core(const u16* __restrict__ u,
                                          const u16* __restrict__ w1T,
                                          const float* __restrict__ b1,
                                          const u16* __restrict__ w2T,
                                          u16* zs, int base, int t, f32x4 acc[4]) {
    const int lane = t & 63, wave = t >> 6;
    const int q = lane >> 4, m = lane & 15;
    const int rowm = min(base + m, N_NODES - 1);
    const bf16x8 a0 = *reinterpret_cast<const bf16x8*>(&u[(size_t)rowm * 64 + q * 8]);
    const bf16x8 a1 = *reinterpret_cast<const bf16x8*>(&u[(size_t)rowm * 64 + 32 + q * 8]);
    f32x4 z[4];
#pragma unroll
    for (int c = 0; c < 4; ++c) z[c] = (f32x4){0.f, 0.f, 0.f, 0.f};
#pragma unroll
    for (int c = 0; c < 4; ++c) {
        const bf16x8 bb0 = *reinterpret_cast<const bf16x8*>(&w1T[(c * 16 + m) * 64 + q * 8]);
        const bf16x8 bb1 = *reinterpret_cast<const bf16x8*>(&w1T[(c * 16 + m) * 64 + 32 + q * 8]);
        z[c] = __builtin_amdgcn_mfma_f32_16x16x32_bf16(a0, bb0, z[c], 0, 0, 0);
        z[c] = __builtin_amdgcn_mfma_f32_16x16x32_bf16(a1, bb1, z[c], 0, 0, 0);
    }
    // C-layout -> A-layout via wave-private LDS rows (no barrier)
#pragma unroll
    for (int c = 0; c < 4; ++c) {
        const float bb = b1[c * 16 + m];
#pragma unroll
        for (int r = 0; r < 4; ++r)
            zs[(wave * 16 + q * 4 + r) * LSTR + c * 16 + m] = f2bf(fmaxf(z[c][r] + bb, 0.f));
    }
    const bf16x8 c0v = *reinterpret_cast<const bf16x8*>(&zs[(wave * 16 + m) * LSTR + q * 8]);
    const bf16x8 c1v = *reinterpret_cast<const bf16x8*>(&zs[(wave * 16 + m) * LSTR + 32 + q * 8]);
#pragma unroll
    for (int c = 0; c < 4; ++c) acc[c] = (f32x4){0.f, 0.f, 0.f, 0.f};
#pragma unroll
    for (int c = 0; c < 4; ++c) {
        const bf16x8 bb0 = *reinterpret_cast<const bf16x8*>(&w2T[(c * 16 + m) * 64 + q * 8]);
        const bf16x8 bb1 = *reinterpret_cast<const bf16x8*>(&w2T[(c * 16 + m) * 64 + 32 + q * 8]);
        acc[c] = __builtin_amdgcn_mfma_f32_16x16x32_bf16(c0v, bb0, acc[c], 0, 0, 0);
        acc[c] = __builtin_amdgcn_mfma_f32_16x16x32_bf16(c1v, bb1, acc[c], 0, 0, 0);
    }
}

// ---------------- two-stage MLP -> global bf16 ----------------
__global__ __launch_bounds__(256, 4) void k_mlp2(const u16* __restrict__ u,
                                                 const u16* __restrict__ w1T,
                                                 const float* __restrict__ b1,
                                                 const u16* __restrict__ w2T,
                                                 const float* __restrict__ b2,
                                                 u16* __restrict__ hout) {
    __shared__ u16 zs[64 * LSTR];
    const int t = threadIdx.x;
    const int lane = t & 63, wave = t >> 6;
    const int q = lane >> 4, m = lane & 15;
    const int base = blockIdx.x * 64 + wave * 16;
    f32x4 acc[4];
    mlp2_core(u, w1T, b1, w2T, zs, base, t, acc);
#pragma unroll
    for (int c = 0; c < 4; ++c) {
        const float bb = b2[c * 16 + m];
#pragma unroll
        for (int r = 0; r < 4; ++r) {
            const int n = base + q * 4 + r;
            if (n < N_NODES) hout[(size_t)n * 64 + c * 16 + m] = f2bf(fmaxf(acc[c][r] + bb, 0.f));
        }
    }
}

// ---------------- two-stage MLP fused with mean-pool numerator ----------------
__global__ __launch_bounds__(256, 4) void k_mlp2_pool(const u16* __restrict__ u,
                                                      const u16* __restrict__ w1T,
                                                      const float* __restrict__ b1,
                                                      const u16* __restrict__ w2T,
                                                      const float* __restrict__ b2,
                                                      const int* __restrict__ bids,
                                                      float* __restrict__ pooled) {
    __shared__ u16 zs[64 * LSTR];
    const int t = threadIdx.x;
    const int lane = t & 63, wave = t >> 6;
    const int q = lane >> 4, m = lane & 15;
    const int base = blockIdx.x * 64 + wave * 16;
    f32x4 acc[4];
    mlp2_core(u, w1T, b1, w2T, zs, base, t, acc);
    // h -> zs node-major (own-wave rows), then run-length segmented atomics
#pragma unroll
    for (int c = 0; c < 4; ++c) {
        const float bb = b2[c * 16 + m];
#pragma unroll
        for (int r = 0; r < 4; ++r)
            zs[(wave * 16 + q * 4 + r) * LSTR + c * 16 + m] = f2bf(fmaxf(acc[c][r] + bb, 0.f));
    }
    if (base < N_NODES) {
        float s = 0.f;
        int cur = bids[base];
        for (int j = 0; j < 16; ++j) {
            const int n = base + j;
            if (n >= N_NODES) break;   // wave-uniform
            const int b = bids[n];
            const float h = bf2f(zs[(wave * 16 + j) * LSTR + lane]);
            if (b != cur) {
                atomicAdd(&pooled[cur * 64 + lane], s);
                cur = b; s = h;
            } else {
                s += h;
            }
        }
        atomicAdd(&pooled[cur * 64 + lane], s);
    }
}

// ---------------- A[:, 0:512] = bf16((pooled/cnt) @ lin_w + lin_b) ----------------
__global__ __launch_bounds__(256) void k_emb(const float* __restrict__ pooled,
                                             const float* __restrict__ counts,
                                             const float* __restrict__ lw,
                                             const float* __restrict__ lb,
                                             u16* __restrict__ A) {
    __shared__ float prow[8][64];
    const int b0 = blockIdx.x * 8;
    const int t = threadIdx.x;
    const int lane = t & 63, wave = t >> 6;
    for (int i = 0; i < 2; ++i) {
        const int r = i * 4 + wave;
        const int b = b0 + r;
        const float c = fmaxf(counts[b], 1.0f);
        prow[r][lane] = pooled[b * 64 + lane] / c;
    }
    __syncthreads();
    for (int o = t; o < 512; o += 256) {
        float acc[8];
#pragma unroll
        for (int r = 0; r < 8; ++r) acc[r] = lb[o];
        for (int k = 0; k < 64; ++k) {
            const float wv = lw[k * 512 + o];
#pragma unroll
            for (int r = 0; r < 8; ++r) acc[r] += prow[r][k] * wv;
        }
#pragma unroll
        for (int r = 0; r < 8; ++r) A[(size_t)(b0 + r) * ASTR + o] = f2bf(acc[r]);
    }
}

// ---------------- A[:, 512:1120] = bf16(entity_embed[pred_pairs]) (+pad) ----------------
__global__ void k_orig(const int* __restrict__ pp, const float* __restrict__ ee,
                       u16* __restrict__ A) {
    const int idx = blockIdx.x * blockDim.x + threadIdx.x;
    if (idx >= BGRAPH * 608) return;
    const int b = idx / 608;
    const int j = idx - b * 608;
    u16 v = 0;
    if (j < 600) {
        const int which = (j >= 300) ? 1 : 0;
        const int cls = pp[b * 2 + which];
        v = f2bf(ee[cls * 300 + (j - which * 300)]);
    }
    A[(size_t)b * ASTR + 512 + j] = v;
}

// ---------------- out = A @ final_w + final_b — barrier-free MFMA ----------------
__global__ __launch_bounds__(256, 4) void k_final(const u16* __restrict__ A,
                                                  const u16* __restrict__ fwT,
                                                  const float* __restrict__ fb,
                                                  float* __restrict__ out) {
    const int t = threadIdx.x;
    const int lane = t & 63, wave = t >> 6;
    const int q = lane >> 4, m = lane & 15;
    const int base = blockIdx.x * 64 + wave * 16;
    const int c0 = blockIdx.y * 64;
    const int rowm = min(base + m, BGRAPH - 1);
    const u16* __restrict__ ar = &A[(size_t)rowm * ASTR];

    f32x4 acc[4];
#pragma unroll
    for (int c = 0; c < 4; ++c) acc[c] = (f32x4){0.f, 0.f, 0.f, 0.f};
#pragma unroll 5
    for (int k0 = 0; k0 < 1120; k0 += 32) {
        const bf16x8 a = *reinterpret_cast<const bf16x8*>(&ar[k0 + q * 8]);
#pragma unroll
        for (int c = 0; c < 4; ++c) {
            const bf16x8 b = *reinterpret_cast<const bf16x8*>(&fwT[(size_t)(c0 + c * 16 + m) * 1120 + k0 + q * 8]);
            acc[c] = __builtin_amdgcn_mfma_f32_16x16x32_bf16(a, b, acc[c], 0, 0, 0);
        }
    }
#pragma unroll
    for (int c = 0; c < 4; ++c) {
        const float bb = fb[c0 + c * 16 + m];
#pragma unroll
        for (int r = 0; r < 4; ++r) {
            const int rr = base + q * 4 + r;
            if (rr < BGRAPH) out[(size_t)rr * 512 + c0 + c * 16 + m] = acc[c][r] + bb;
        }
    }
}

extern "C" void kernel_launch(void* const* d_in, const int* in_sizes, int n_in,
                              void* d_out, int out_size, void* d_ws, size_t ws_size,
                              hipStream_t stream) {
    const int*   pred_pairs = (const int*)d_in[0];
    const float* x          = (const float*)d_in[1];
    const int*   ei         = (const int*)d_in[2];
    const int*   bids       = (const int*)d_in[3];
    const float* ee         = (const float*)d_in[4];
    const float* w1_0 = (const float*)d_in[5];
    const float* b1_0 = (const float*)d_in[6];
    const float* w2_0 = (const float*)d_in[7];
    const float* b2_0 = (const float*)d_in[8];
    const float* w1_1 = (const float*)d_in[9];
    const float* b1_1 = (const float*)d_in[10];
    const float* w2_1 = (const float*)d_in[11];
    const float* b2_1 = (const float*)d_in[12];
    const float* w1_2 = (const float*)d_in[13];
    const float* b1_2 = (const float*)d_in[14];
    const float* w2_2 = (const float*)d_in[15];
    const float* b2_2 = (const float*)d_in[16];
    const float* lin_w   = (const float*)d_in[17];
    const float* lin_b   = (const float*)d_in[18];
    const float* final_w = (const float*)d_in[19];
    const float* final_b = (const float*)d_in[20];
    float* out = (float*)d_out;

    // workspace layout (16-B aligned regions)
    u16*   Y      = (u16*)d_ws;                          // 6,400,000 u16
    u16*   Hb     = Y + (size_t)N_NODES * 64;            // 6,400,000 u16
    u16*   U      = Hb + (size_t)N_NODES * 64;           // 6,400,000 u16
    int*   csr2   = (int*)(U + (size_t)N_NODES * 64);    // 4,800,000 int
    int*   deg    = csr2 + (size_t)N_NODES * CAP;        // 100,000 int
    float* pooled = (float*)(deg + N_NODES);             // 256,000 f
    float* counts = pooled + (size_t)BGRAPH * 64;        // 4,000 f
    u16*   A      = (u16*)(counts + BGRAPH);             // 4,480,000 u16 (padded)
    u16*   w0T    = A + (size_t)BGRAPH * ASTR;           // 28,672 u16
    u16*   fwT    = w0T + 64 * 448;                      // 573,440 u16
    u16*   wT5    = fwT + (size_t)512 * 1120;            // 5*4096 u16
    u16*   w2T0   = wT5;
    u16*   w1T1   = wT5 + 4096;
    u16*   w2T1   = wT5 + 8192;
    u16*   w1T2   = wT5 + 12288;
    u16*   w2T2   = wT5 + 16384;

    // zero deg + pooled + counts (adjacent)
    hipMemsetAsync(deg, 0, (size_t)(N_NODES + BGRAPH * 64 + BGRAPH) * sizeof(int), stream);

    k_prep_w0<<<(64 * 448 + 255) / 256, 256, 0, stream>>>(w1_0, w0T);
    k_prep_fw<<<(512 * 1120 + 255) / 256, 256, 0, stream>>>(final_w, fwT);
    k_prep_w5<<<80, 256, 0, stream>>>(w2_0, w1_1, w2_1, w1_2, w2_2, wT5);
    k_fill<<<(N_EDGES + 255) / 256, 256, 0, stream>>>(ei, deg, csr2);
    k_counts<<<(N_NODES + 255) / 256, 256, 0, stream>>>(bids, counts);
    k_gemm_xw<<<(N_NODES + 63) / 64, 256, 0, stream>>>(x, w0T, Y);
    // layer 0
    k_agg<1><<<(N_NODES + 3) / 4, 256, 0, stream>>>(Y, deg, csr2, b1_0, U);
    k_mlp1<<<(N_NODES + 63) / 64, 256, 0, stream>>>(U, w2T0, b2_0, Hb);
    // layer 1
    k_agg<0><<<(N_NODES + 3) / 4, 256, 0, stream>>>(Hb, deg, csr2, b1_0, U);
    k_mlp2<<<(N_NODES + 63) / 64, 256, 0, stream>>>(U, w1T1, b1_1, w2T1, b2_1, Y);
    // layer 2 + pool
    k_agg<0><<<(N_NODES + 3) / 4, 256, 0, stream>>>(Y, deg, csr2, b1_0, U);
    k_mlp2_pool<<<(N_NODES + 63) / 64, 256, 0, stream>>>(U, w1T2, b1_2, w2T2, b2_2, bids, pooled);
    // head
    k_emb<<<BGRAPH / 8, 256, 0, stream>>>(pooled, counts, lin_w, lin_b, A);
    k_orig<<<(BGRAPH * 608 + 255) / 256, 256, 0, stream>>>(pred_pairs, ee, A);
    k_final<<<dim3((BGRAPH + 63) / 64, 8), 256, 0, stream>>>(A, fwT, final_b, out);
}